// Round 1
// baseline (587.017 us; speedup 1.0000x reference)
//
#include <hip/hip_runtime.h>
#include <hip/hip_fp16.h>

// Problem: B=64, L=512, D=512, A=512
//   F_p = tanh(P @ W), F_h = tanh(H @ W)        [f16 in ws, split-MFMA for accuracy]
//   S = F_p @ F_h^T ; attn = softmax_rows(S)    [fused, attn f16 in ws]
//   betas  = attn   @ H  -> d_out[0 .. 16M)
//   alphas = attn^T @ P  -> d_out[16M .. 32M)
// Workspace: F_p|F_h (2*16.78M f16 = 67.1MB) + attn (33.6MB) = 100.7MB

#define NB 64
#define NL 512
#define ND 512
#define BATCH_ELEMS (512 * 512)          // 262144
#define TOT_ELEMS   ((size_t)NB * NL * ND) // 16777216

typedef _Float16 h8 __attribute__((ext_vector_type(8)));
typedef float f4 __attribute__((ext_vector_type(4)));

// LDS tile layout: [row][32 k] f16, 16B chunks XOR-swizzled by ((row>>1)&3)
// -> 16B-aligned b128 access, 2-way-max bank aliasing (free on CDNA4).
__device__ __forceinline__ int swz(int row, int chunk) {
    return (row << 5) + ((chunk ^ ((row >> 1) & 3)) << 3);
}

__device__ __forceinline__ float fast_tanh(float x) {
    float e = __expf(2.0f * x);          // inf-safe: x>>0 -> 1, x<<0 -> -1
    return 1.0f - 2.0f / (e + 1.0f);
}

// ---------------- Kernel 1: F = tanh(X @ W), split f16 (hi/lo) MFMA ----------
__global__ __launch_bounds__(256) void proj_tanh_kernel(
    const float* __restrict__ P, const float* __restrict__ H,
    const float* __restrict__ W, _Float16* __restrict__ Fout)
{
    __shared__ __align__(16) _Float16 AsH[128 * 32], AsL[128 * 32];
    __shared__ __align__(16) _Float16 BsH[128 * 32], BsL[128 * 32];

    const int z = blockIdx.z;
    const float* X = z ? H : P;
    _Float16* F = Fout + (size_t)z * TOT_ELEMS;
    const int r0 = blockIdx.y * 128;   // rows in [0, 32768)
    const int n0 = blockIdx.x * 128;   // cols in [0, 512)

    const int t = threadIdx.x;
    const int lane = t & 63, w = t >> 6;
    const int q = lane >> 4, c = lane & 15;
    const int wm = w >> 1, wn = w & 1;

    f4 acc[4][4] = {};

    const int ar = t >> 1, akq = (t & 1) << 4;   // A stage: row, k-offset 0/16
    const int bk = t >> 3, bn0 = (t & 7) << 4;   // B stage: k, n-offset

    for (int k0 = 0; k0 < 512; k0 += 32) {
        // stage A tile (128x32 fp32 -> hi/lo f16)
        {
            const float* ap = X + (size_t)(r0 + ar) * 512 + k0 + akq;
            float av[16];
            *(float4*)&av[0]  = ((const float4*)ap)[0];
            *(float4*)&av[4]  = ((const float4*)ap)[1];
            *(float4*)&av[8]  = ((const float4*)ap)[2];
            *(float4*)&av[12] = ((const float4*)ap)[3];
            const int cbase = akq >> 3;
#pragma unroll
            for (int jj = 0; jj < 2; ++jj) {
                h8 hv, lv;
#pragma unroll
                for (int i = 0; i < 8; ++i) {
                    float x = av[jj * 8 + i];
                    _Float16 hx = (_Float16)x;
                    hv[i] = hx;
                    lv[i] = (_Float16)(x - (float)hx);
                }
                *(h8*)&AsH[swz(ar, cbase + jj)] = hv;
                *(h8*)&AsL[swz(ar, cbase + jj)] = lv;
            }
        }
        // stage B tile: W[k][n] fp32 -> Bs[n][k] hi/lo f16 (transpose)
        {
            const float* bp = W + (size_t)(k0 + bk) * 512 + n0 + bn0;
            float bv[16];
            *(float4*)&bv[0]  = ((const float4*)bp)[0];
            *(float4*)&bv[4]  = ((const float4*)bp)[1];
            *(float4*)&bv[8]  = ((const float4*)bp)[2];
            *(float4*)&bv[12] = ((const float4*)bp)[3];
#pragma unroll
            for (int j = 0; j < 16; ++j) {
                int n = bn0 + j;
                int off = swz(n, bk >> 3) + (bk & 7);
                _Float16 hx = (_Float16)bv[j];
                BsH[off] = hx;
                BsL[off] = (_Float16)(bv[j] - (float)hx);
            }
        }
        __syncthreads();

        h8 aH[4], aL[4], bH[4], bL[4];
#pragma unroll
        for (int mi = 0; mi < 4; ++mi) {
            int row = wm * 64 + mi * 16 + c;
            aH[mi] = *(const h8*)&AsH[swz(row, q)];
            aL[mi] = *(const h8*)&AsL[swz(row, q)];
        }
#pragma unroll
        for (int ni = 0; ni < 4; ++ni) {
            int col = wn * 64 + ni * 16 + c;
            bH[ni] = *(const h8*)&BsH[swz(col, q)];
            bL[ni] = *(const h8*)&BsL[swz(col, q)];
        }
#pragma unroll
        for (int mi = 0; mi < 4; ++mi)
#pragma unroll
            for (int ni = 0; ni < 4; ++ni) {
                acc[mi][ni] = __builtin_amdgcn_mfma_f32_16x16x32_f16(aH[mi], bH[ni], acc[mi][ni], 0, 0, 0);
                acc[mi][ni] = __builtin_amdgcn_mfma_f32_16x16x32_f16(aH[mi], bL[ni], acc[mi][ni], 0, 0, 0);
                acc[mi][ni] = __builtin_amdgcn_mfma_f32_16x16x32_f16(aL[mi], bH[ni], acc[mi][ni], 0, 0, 0);
            }
        __syncthreads();
    }

#pragma unroll
    for (int mi = 0; mi < 4; ++mi)
#pragma unroll
        for (int ni = 0; ni < 4; ++ni) {
            int col = n0 + wn * 64 + ni * 16 + c;
            int rowb = r0 + wm * 64 + mi * 16 + q * 4;
#pragma unroll
            for (int r = 0; r < 4; ++r)
                F[(size_t)(rowb + r) * 512 + col] = (_Float16)fast_tanh(acc[mi][ni][r]);
        }
}

// ---------------- Kernel 2: S = F_p @ F_h^T, row softmax -> attn f16 ---------
__global__ __launch_bounds__(256) void score_softmax_kernel(
    const _Float16* __restrict__ Fbase, _Float16* __restrict__ attn)
{
    __shared__ __align__(16) _Float16 As[64 * 32];
    __shared__ __align__(16) _Float16 Bs[512 * 32];
    __shared__ float redM[4 * 64], redS[4 * 64];

    const _Float16* Fp = Fbase;
    const _Float16* Fh = Fbase + TOT_ELEMS;
    const int b = blockIdx.y;
    const int p0 = blockIdx.x * 64;
    const size_t fb = (size_t)b * BATCH_ELEMS;

    const int t = threadIdx.x, lane = t & 63, w = t >> 6;
    const int q = lane >> 4, c = lane & 15;

    f4 acc[4][8] = {};

    for (int k0 = 0; k0 < 512; k0 += 32) {
        {   // A: F_p rows [p0, p0+64) x 32k  (direct, f16)
            int row = t >> 2, ch = t & 3;
            *(h8*)&As[swz(row, ch)] =
                *(const h8*)(Fp + fb + (size_t)(p0 + row) * 512 + k0 + ch * 8);
        }
        {   // B: F_h rows [0,512) x 32k -> Bs[h][k] (direct: B[k][n]=F_h[n][k])
#pragma unroll
            for (int rr = 0; rr < 2; ++rr) {
                int row = t * 2 + rr;
#pragma unroll
                for (int ch = 0; ch < 4; ++ch)
                    *(h8*)&Bs[swz(row, ch)] =
                        *(const h8*)(Fh + fb + (size_t)row * 512 + k0 + ch * 8);
            }
        }
        __syncthreads();

        h8 a[4], bb[8];
#pragma unroll
        for (int mt = 0; mt < 4; ++mt) a[mt] = *(const h8*)&As[swz(mt * 16 + c, q)];
#pragma unroll
        for (int nt = 0; nt < 8; ++nt) bb[nt] = *(const h8*)&Bs[swz(w * 128 + nt * 16 + c, q)];
#pragma unroll
        for (int mt = 0; mt < 4; ++mt)
#pragma unroll
            for (int nt = 0; nt < 8; ++nt)
                acc[mt][nt] = __builtin_amdgcn_mfma_f32_16x16x32_f16(a[mt], bb[nt], acc[mt][nt], 0, 0, 0);
        __syncthreads();
    }

    // ---- softmax over the 512 cols; rows owned: mt*16 + q*4 + r ----
    float rmax[4][4];
#pragma unroll
    for (int mt = 0; mt < 4; ++mt)
#pragma unroll
        for (int r = 0; r < 4; ++r) {
            float m = acc[mt][0][r];
#pragma unroll
            for (int nt = 1; nt < 8; ++nt) m = fmaxf(m, acc[mt][nt][r]);
            rmax[mt][r] = m;
        }
#pragma unroll
    for (int s = 1; s < 16; s <<= 1)
#pragma unroll
        for (int mt = 0; mt < 4; ++mt)
#pragma unroll
            for (int r = 0; r < 4; ++r)
                rmax[mt][r] = fmaxf(rmax[mt][r], __shfl_xor(rmax[mt][r], s, 64));
    if (c == 0)
#pragma unroll
        for (int mt = 0; mt < 4; ++mt)
#pragma unroll
            for (int r = 0; r < 4; ++r)
                redM[w * 64 + mt * 16 + q * 4 + r] = rmax[mt][r];
    __syncthreads();

    float gmax[4][4];
#pragma unroll
    for (int mt = 0; mt < 4; ++mt)
#pragma unroll
        for (int r = 0; r < 4; ++r) {
            int row = mt * 16 + q * 4 + r;
            float m = redM[row];
#pragma unroll
            for (int w4 = 1; w4 < 4; ++w4) m = fmaxf(m, redM[w4 * 64 + row]);
            gmax[mt][r] = m;
        }

    float rsum[4][4] = {};
#pragma unroll
    for (int mt = 0; mt < 4; ++mt)
#pragma unroll
        for (int nt = 0; nt < 8; ++nt)
#pragma unroll
            for (int r = 0; r < 4; ++r) {
                float e = __expf(acc[mt][nt][r] - gmax[mt][r]);
                acc[mt][nt][r] = e;
                rsum[mt][r] += e;
            }
#pragma unroll
    for (int s = 1; s < 16; s <<= 1)
#pragma unroll
        for (int mt = 0; mt < 4; ++mt)
#pragma unroll
            for (int r = 0; r < 4; ++r)
                rsum[mt][r] += __shfl_xor(rsum[mt][r], s, 64);
    if (c == 0)
#pragma unroll
        for (int mt = 0; mt < 4; ++mt)
#pragma unroll
            for (int r = 0; r < 4; ++r)
                redS[w * 64 + mt * 16 + q * 4 + r] = rsum[mt][r];
    __syncthreads();

    float inv[4][4];
#pragma unroll
    for (int mt = 0; mt < 4; ++mt)
#pragma unroll
        for (int r = 0; r < 4; ++r) {
            int row = mt * 16 + q * 4 + r;
            float s = redS[row] + redS[64 + row] + redS[128 + row] + redS[192 + row];
            inv[mt][r] = 1.0f / s;
        }

#pragma unroll
    for (int mt = 0; mt < 4; ++mt)
#pragma unroll
        for (int nt = 0; nt < 8; ++nt) {
            int col = w * 128 + nt * 16 + c;
#pragma unroll
            for (int r = 0; r < 4; ++r) {
                int row = p0 + mt * 16 + q * 4 + r;
                attn[fb + (size_t)row * 512 + col] = (_Float16)(acc[mt][nt][r] * inv[mt][r]);
            }
        }
}

// ------------- Kernels 3/4: C = A(^T) @ B, A=attn f16, B=fp32->f16 -----------
template <bool TRANS_A>
__global__ __launch_bounds__(256) void out_gemm_kernel(
    const _Float16* __restrict__ Amat, const float* __restrict__ Bmat,
    float* __restrict__ Cout)
{
    __shared__ __align__(16) _Float16 As[128 * 32];
    __shared__ __align__(16) _Float16 Bs[128 * 32];

    const int b = blockIdx.z;
    const int bn = blockIdx.x * 128, bm = blockIdx.y * 128;
    const size_t base = (size_t)b * BATCH_ELEMS;

    const int t = threadIdx.x, lane = t & 63, w = t >> 6;
    const int q = lane >> 4, c = lane & 15;
    const int wm = w >> 1, wn = w & 1;

    f4 acc[4][4] = {};

    for (int k0 = 0; k0 < 512; k0 += 32) {
        if (!TRANS_A) {  // As[m=p][k=h] <- attn[p][h] direct
            int row = t >> 1, cp = (t & 1) * 2;
            const _Float16* ap = Amat + base + (size_t)(bm + row) * 512 + k0 + cp * 8;
            *(h8*)&As[swz(row, cp)]     = ((const h8*)ap)[0];
            *(h8*)&As[swz(row, cp + 1)] = ((const h8*)ap)[1];
        } else {         // As[m=h][k=p] <- attn[p][h] transposed
            int kk = t >> 3, m0 = (t & 7) * 16;
            const _Float16* ap = Amat + base + (size_t)(k0 + kk) * 512 + bm + m0;
            h8 x0 = ((const h8*)ap)[0];
            h8 x1 = ((const h8*)ap)[1];
#pragma unroll
            for (int j = 0; j < 8; ++j) {
                As[swz(m0 + j, kk >> 3) + (kk & 7)]     = x0[j];
                As[swz(m0 + 8 + j, kk >> 3) + (kk & 7)] = x1[j];
            }
        }
        {   // Bs[n=d][k] <- Bmat[k][d] transposed + fp32->f16
            int kk = t >> 3, n0l = (t & 7) * 16;
            const float* bp = Bmat + base + (size_t)(k0 + kk) * 512 + bn + n0l;
            float bv[16];
            *(float4*)&bv[0]  = ((const float4*)bp)[0];
            *(float4*)&bv[4]  = ((const float4*)bp)[1];
            *(float4*)&bv[8]  = ((const float4*)bp)[2];
            *(float4*)&bv[12] = ((const float4*)bp)[3];
#pragma unroll
            for (int j = 0; j < 16; ++j)
                Bs[swz(n0l + j, kk >> 3) + (kk & 7)] = (_Float16)bv[j];
        }
        __syncthreads();

        h8 a[4], bb[4];
#pragma unroll
        for (int mi = 0; mi < 4; ++mi) a[mi] = *(const h8*)&As[swz(wm * 64 + mi * 16 + c, q)];
#pragma unroll
        for (int ni = 0; ni < 4; ++ni) bb[ni] = *(const h8*)&Bs[swz(wn * 64 + ni * 16 + c, q)];
#pragma unroll
        for (int mi = 0; mi < 4; ++mi)
#pragma unroll
            for (int ni = 0; ni < 4; ++ni)
                acc[mi][ni] = __builtin_amdgcn_mfma_f32_16x16x32_f16(a[mi], bb[ni], acc[mi][ni], 0, 0, 0);
        __syncthreads();
    }

#pragma unroll
    for (int mi = 0; mi < 4; ++mi)
#pragma unroll
        for (int ni = 0; ni < 4; ++ni) {
            int col = bn + wn * 64 + ni * 16 + c;
            int rowb = bm + wm * 64 + mi * 16 + q * 4;
#pragma unroll
            for (int r = 0; r < 4; ++r)
                Cout[base + (size_t)(rowb + r) * 512 + col] = acc[mi][ni][r];
        }
}

extern "C" void kernel_launch(void* const* d_in, const int* in_sizes, int n_in,
                              void* d_out, int out_size, void* d_ws, size_t ws_size,
                              hipStream_t stream) {
    const float* P = (const float*)d_in[0];
    const float* H = (const float*)d_in[1];
    const float* W = (const float*)d_in[2];
    float* out = (float*)d_out;

    _Float16* F    = (_Float16*)d_ws;            // F_p | F_h : 2*16777216 f16
    _Float16* attn = F + 2 * TOT_ELEMS;          // 16777216 f16  (needs ~100.7MB ws)

    proj_tanh_kernel<<<dim3(4, 256, 2), 256, 0, stream>>>(P, H, W, F);
    score_softmax_kernel<<<dim3(8, NB), 256, 0, stream>>>(F, attn);
    out_gemm_kernel<false><<<dim3(4, 4, NB), 256, 0, stream>>>(attn, H, out);
    out_gemm_kernel<true><<<dim3(4, 4, NB), 256, 0, stream>>>(attn, P, out + TOT_ELEMS);
}

// Round 2
// 499.717 us; speedup vs baseline: 1.1747x; 1.1747x over previous
//
#include <hip/hip_runtime.h>
#include <hip/hip_fp16.h>

// Problem: B=64, L=512, D=512, A=512
//   F_p = tanh(P @ W), F_h = tanh(H @ W)        [f16 in ws, split-MFMA for accuracy]
//   S = F_p @ F_h^T ; attn = softmax_rows(S)    [fused, attn f16 in ws]
//   betas  = attn   @ H  -> d_out[0 .. 16M)
//   alphas = attn^T @ P  -> d_out[16M .. 32M)
//
// ws layout (f16 elems), total 100.66 MB (same as R1):
//   [0, 33554432)          F_p|F_h   -- dead after score; reused for PT|HT
//   [33554432, 50331648)   WT_H|WT_L (1MB, dead after proj) then attn (score output)

#define NB 64
#define NL 512
#define ND 512
#define BATCH_ELEMS (512 * 512)            // 262144
#define TOT_ELEMS   ((size_t)NB * NL * ND) // 16777216

typedef _Float16 h8 __attribute__((ext_vector_type(8)));
typedef float f4 __attribute__((ext_vector_type(4)));

// LDS tile layout: [row][32 k] f16, 16B chunks XOR-swizzled by ((row>>1)^(row>>4))&3.
// row>>4 term spreads scalar transpose writes (m stride 16) across bank quads.
__device__ __forceinline__ int swz(int row, int chunk) {
    return (row << 5) + ((chunk ^ (((row >> 1) ^ (row >> 4)) & 3)) << 3);
}

__device__ __forceinline__ float fast_tanh(float x) {
    float e = __expf(2.0f * x);            // inf-safe: x>>0 -> 1, x<<0 -> -1
    return 1.0f - 2.0f / (e + 1.0f);
}

// ------------- Prep: out[c][r] = f16(src[r][c]) (+ lo residual), 512x512/batch
template <bool WITH_LO>
__global__ __launch_bounds__(256) void transpose_f16_kernel(
    const float* __restrict__ src, _Float16* __restrict__ dstH,
    _Float16* __restrict__ dstL)
{
    __shared__ float tile[64 * 68];
    const size_t base = (size_t)blockIdx.z * BATCH_ELEMS;
    const int r0 = blockIdx.y * 64, c0 = blockIdx.x * 64;
    const int t = threadIdx.x;
    {
        int r = t >> 2, cq = (t & 3) * 16;
        const float* sp = src + base + (size_t)(r0 + r) * 512 + c0 + cq;
        *(float4*)&tile[r * 68 + cq]      = ((const float4*)sp)[0];
        *(float4*)&tile[r * 68 + cq + 4]  = ((const float4*)sp)[1];
        *(float4*)&tile[r * 68 + cq + 8]  = ((const float4*)sp)[2];
        *(float4*)&tile[r * 68 + cq + 12] = ((const float4*)sp)[3];
    }
    __syncthreads();
    {
        int c = t >> 2, rq = (t & 3) * 16;
        _Float16 hv[16], lv[16];
#pragma unroll
        for (int j = 0; j < 16; ++j) {
            float v = tile[(rq + j) * 68 + c];
            hv[j] = (_Float16)v;
            if (WITH_LO) lv[j] = (_Float16)(v - (float)hv[j]);
        }
        _Float16* dp = dstH + base + (size_t)(c0 + c) * 512 + r0 + rq;
        *(h8*)dp = *(h8*)&hv[0];
        *(h8*)(dp + 8) = *(h8*)&hv[8];
        if (WITH_LO) {
            _Float16* dl = dstL + base + (size_t)(c0 + c) * 512 + r0 + rq;
            *(h8*)dl = *(h8*)&lv[0];
            *(h8*)(dl + 8) = *(h8*)&lv[8];
        }
    }
}

// ---------------- Kernel 1: F = tanh(X @ W), split f16 (hi/lo) MFMA ----------
// WT_H/WT_L are precomputed f16 [n][k] (transposed W), so B-staging is a copy.
__global__ __launch_bounds__(256) void proj_tanh_kernel(
    const float* __restrict__ P, const float* __restrict__ H,
    const _Float16* __restrict__ WTH, const _Float16* __restrict__ WTL,
    _Float16* __restrict__ Fout)
{
    __shared__ __align__(16) _Float16 AsH[128 * 32], AsL[128 * 32];
    __shared__ __align__(16) _Float16 BsH[128 * 32], BsL[128 * 32];

    const int z = blockIdx.z;
    const float* X = z ? H : P;
    _Float16* F = Fout + (size_t)z * TOT_ELEMS;
    const int r0 = blockIdx.x * 128;   // row tile fastest -> col-blocks of same
    const int n0 = blockIdx.y * 128;   // rows land on same XCD (ids differ by 256)

    const int t = threadIdx.x;
    const int lane = t & 63, w = t >> 6;
    const int q = lane >> 4, c = lane & 15;
    const int wm = w >> 1, wn = w & 1;

    f4 acc[4][4] = {};

    const int ar = t >> 1, akq = (t & 1) << 4;   // A stage: row, k-offset 0/16
    const int br = t >> 1, bcp = (t & 1) << 1;   // B stage: n-row, chunk pair

    for (int k0 = 0; k0 < 512; k0 += 32) {
        // stage A tile (128x32 fp32 -> hi/lo f16)
        {
            const float* ap = X + (size_t)(r0 + ar) * 512 + k0 + akq;
            float av[16];
            *(float4*)&av[0]  = ((const float4*)ap)[0];
            *(float4*)&av[4]  = ((const float4*)ap)[1];
            *(float4*)&av[8]  = ((const float4*)ap)[2];
            *(float4*)&av[12] = ((const float4*)ap)[3];
            const int cbase = akq >> 3;
#pragma unroll
            for (int jj = 0; jj < 2; ++jj) {
                h8 hv, lv;
#pragma unroll
                for (int i = 0; i < 8; ++i) {
                    float x = av[jj * 8 + i];
                    _Float16 hx = (_Float16)x;
                    hv[i] = hx;
                    lv[i] = (_Float16)(x - (float)hx);
                }
                *(h8*)&AsH[swz(ar, cbase + jj)] = hv;
                *(h8*)&AsL[swz(ar, cbase + jj)] = lv;
            }
        }
        // stage B tile: pure vector copy from precomputed WT
        {
            const _Float16* bh = WTH + (size_t)(n0 + br) * 512 + k0 + bcp * 8;
            const _Float16* bl = WTL + (size_t)(n0 + br) * 512 + k0 + bcp * 8;
            *(h8*)&BsH[swz(br, bcp)]     = ((const h8*)bh)[0];
            *(h8*)&BsH[swz(br, bcp + 1)] = ((const h8*)bh)[1];
            *(h8*)&BsL[swz(br, bcp)]     = ((const h8*)bl)[0];
            *(h8*)&BsL[swz(br, bcp + 1)] = ((const h8*)bl)[1];
        }
        __syncthreads();

        h8 aH[4], aL[4], bH[4], bL[4];
#pragma unroll
        for (int mi = 0; mi < 4; ++mi) {
            int row = wm * 64 + mi * 16 + c;
            aH[mi] = *(const h8*)&AsH[swz(row, q)];
            aL[mi] = *(const h8*)&AsL[swz(row, q)];
        }
#pragma unroll
        for (int ni = 0; ni < 4; ++ni) {
            int col = wn * 64 + ni * 16 + c;
            bH[ni] = *(const h8*)&BsH[swz(col, q)];
            bL[ni] = *(const h8*)&BsL[swz(col, q)];
        }
#pragma unroll
        for (int mi = 0; mi < 4; ++mi)
#pragma unroll
            for (int ni = 0; ni < 4; ++ni) {
                acc[mi][ni] = __builtin_amdgcn_mfma_f32_16x16x32_f16(aH[mi], bH[ni], acc[mi][ni], 0, 0, 0);
                acc[mi][ni] = __builtin_amdgcn_mfma_f32_16x16x32_f16(aH[mi], bL[ni], acc[mi][ni], 0, 0, 0);
                acc[mi][ni] = __builtin_amdgcn_mfma_f32_16x16x32_f16(aL[mi], bH[ni], acc[mi][ni], 0, 0, 0);
            }
        __syncthreads();
    }

#pragma unroll
    for (int mi = 0; mi < 4; ++mi)
#pragma unroll
        for (int ni = 0; ni < 4; ++ni) {
            int col = n0 + wn * 64 + ni * 16 + c;
            int rowb = r0 + wm * 64 + mi * 16 + q * 4;
#pragma unroll
            for (int r = 0; r < 4; ++r)
                F[(size_t)(rowb + r) * 512 + col] = (_Float16)fast_tanh(acc[mi][ni][r]);
        }
}

// ---------------- Kernel 2: S = F_p @ F_h^T, row softmax -> attn f16 ---------
__global__ __launch_bounds__(256) void score_softmax_kernel(
    const _Float16* __restrict__ Fbase, _Float16* __restrict__ attn)
{
    __shared__ __align__(16) _Float16 As[64 * 32];
    __shared__ __align__(16) _Float16 Bs[512 * 32];
    __shared__ float redM[4 * 64], redS[4 * 64];

    const _Float16* Fp = Fbase;
    const _Float16* Fh = Fbase + TOT_ELEMS;
    const int b = blockIdx.y;
    const int p0 = blockIdx.x * 64;
    const size_t fb = (size_t)b * BATCH_ELEMS;

    const int t = threadIdx.x, lane = t & 63, w = t >> 6;
    const int q = lane >> 4, c = lane & 15;

    f4 acc[4][8] = {};

    for (int k0 = 0; k0 < 512; k0 += 32) {
        {   // A: F_p rows [p0, p0+64) x 32k  (direct, f16)
            int row = t >> 2, ch = t & 3;
            *(h8*)&As[swz(row, ch)] =
                *(const h8*)(Fp + fb + (size_t)(p0 + row) * 512 + k0 + ch * 8);
        }
        {   // B: F_h rows [0,512) x 32k -> Bs[h][k] (direct: B[k][n]=F_h[n][k])
#pragma unroll
            for (int rr = 0; rr < 2; ++rr) {
                int row = t * 2 + rr;
#pragma unroll
                for (int ch = 0; ch < 4; ++ch)
                    *(h8*)&Bs[swz(row, ch)] =
                        *(const h8*)(Fh + fb + (size_t)row * 512 + k0 + ch * 8);
            }
        }
        __syncthreads();

        h8 a[4], bb[8];
#pragma unroll
        for (int mt = 0; mt < 4; ++mt) a[mt] = *(const h8*)&As[swz(mt * 16 + c, q)];
#pragma unroll
        for (int nt = 0; nt < 8; ++nt) bb[nt] = *(const h8*)&Bs[swz(w * 128 + nt * 16 + c, q)];
#pragma unroll
        for (int mt = 0; mt < 4; ++mt)
#pragma unroll
            for (int nt = 0; nt < 8; ++nt)
                acc[mt][nt] = __builtin_amdgcn_mfma_f32_16x16x32_f16(a[mt], bb[nt], acc[mt][nt], 0, 0, 0);
        __syncthreads();
    }

    // ---- softmax over the 512 cols; rows owned: mt*16 + q*4 + r ----
    float rmax[4][4];
#pragma unroll
    for (int mt = 0; mt < 4; ++mt)
#pragma unroll
        for (int r = 0; r < 4; ++r) {
            float m = acc[mt][0][r];
#pragma unroll
            for (int nt = 1; nt < 8; ++nt) m = fmaxf(m, acc[mt][nt][r]);
            rmax[mt][r] = m;
        }
#pragma unroll
    for (int s = 1; s < 16; s <<= 1)
#pragma unroll
        for (int mt = 0; mt < 4; ++mt)
#pragma unroll
            for (int r = 0; r < 4; ++r)
                rmax[mt][r] = fmaxf(rmax[mt][r], __shfl_xor(rmax[mt][r], s, 64));
    if (c == 0)
#pragma unroll
        for (int mt = 0; mt < 4; ++mt)
#pragma unroll
            for (int r = 0; r < 4; ++r)
                redM[w * 64 + mt * 16 + q * 4 + r] = rmax[mt][r];
    __syncthreads();

    float gmax[4][4];
#pragma unroll
    for (int mt = 0; mt < 4; ++mt)
#pragma unroll
        for (int r = 0; r < 4; ++r) {
            int row = mt * 16 + q * 4 + r;
            float m = redM[row];
#pragma unroll
            for (int w4 = 1; w4 < 4; ++w4) m = fmaxf(m, redM[w4 * 64 + row]);
            gmax[mt][r] = m;
        }

    float rsum[4][4] = {};
#pragma unroll
    for (int mt = 0; mt < 4; ++mt)
#pragma unroll
        for (int nt = 0; nt < 8; ++nt)
#pragma unroll
            for (int r = 0; r < 4; ++r) {
                float e = __expf(acc[mt][nt][r] - gmax[mt][r]);
                acc[mt][nt][r] = e;
                rsum[mt][r] += e;
            }
#pragma unroll
    for (int s = 1; s < 16; s <<= 1)
#pragma unroll
        for (int mt = 0; mt < 4; ++mt)
#pragma unroll
            for (int r = 0; r < 4; ++r)
                rsum[mt][r] += __shfl_xor(rsum[mt][r], s, 64);
    if (c == 0)
#pragma unroll
        for (int mt = 0; mt < 4; ++mt)
#pragma unroll
            for (int r = 0; r < 4; ++r)
                redS[w * 64 + mt * 16 + q * 4 + r] = rsum[mt][r];
    __syncthreads();

    float inv[4][4];
#pragma unroll
    for (int mt = 0; mt < 4; ++mt)
#pragma unroll
        for (int r = 0; r < 4; ++r) {
            int row = mt * 16 + q * 4 + r;
            float s = redS[row] + redS[64 + row] + redS[128 + row] + redS[192 + row];
            inv[mt][r] = 1.0f / s;
        }

#pragma unroll
    for (int mt = 0; mt < 4; ++mt)
#pragma unroll
        for (int nt = 0; nt < 8; ++nt) {
            int col = w * 128 + nt * 16 + c;
#pragma unroll
            for (int r = 0; r < 4; ++r) {
                int row = p0 + mt * 16 + q * 4 + r;
                attn[fb + (size_t)row * 512 + col] = (_Float16)(acc[mt][nt][r] * inv[mt][r]);
            }
        }
}

// ------------- Kernels 3/4: C = A(^T) @ B, A=attn f16, B=precomputed BT f16 --
template <bool TRANS_A>
__global__ __launch_bounds__(256) void out_gemm_kernel(
    const _Float16* __restrict__ Amat, const _Float16* __restrict__ BT,
    float* __restrict__ Cout)
{
    __shared__ __align__(16) _Float16 As[128 * 32];
    __shared__ __align__(16) _Float16 Bs[128 * 32];

    const int b = blockIdx.z;
    const int bn = blockIdx.x * 128, bm = blockIdx.y * 128;
    const size_t base = (size_t)b * BATCH_ELEMS;

    const int t = threadIdx.x, lane = t & 63, w = t >> 6;
    const int q = lane >> 4, c = lane & 15;
    const int wm = w >> 1, wn = w & 1;

    f4 acc[4][4] = {};

    for (int k0 = 0; k0 < 512; k0 += 32) {
        if (!TRANS_A) {  // As[m=p][k=h] <- attn[p][h] direct
            int row = t >> 1, cp = (t & 1) * 2;
            const _Float16* ap = Amat + base + (size_t)(bm + row) * 512 + k0 + cp * 8;
            *(h8*)&As[swz(row, cp)]     = ((const h8*)ap)[0];
            *(h8*)&As[swz(row, cp + 1)] = ((const h8*)ap)[1];
        } else {         // As[m=h][k=p] <- attn[p][h] transposed in LDS
            int kk = t >> 3, m0 = (t & 7) * 16;
            const _Float16* ap = Amat + base + (size_t)(k0 + kk) * 512 + bm + m0;
            h8 x0 = ((const h8*)ap)[0];
            h8 x1 = ((const h8*)ap)[1];
#pragma unroll
            for (int j = 0; j < 8; ++j) {
                As[swz(m0 + j, kk >> 3) + (kk & 7)]     = x0[j];
                As[swz(m0 + 8 + j, kk >> 3) + (kk & 7)] = x1[j];
            }
        }
        {   // Bs[n=d][k] <- BT[d][k] direct vector copy
            int row = t >> 1, cp = (t & 1) * 2;
            const _Float16* bp = BT + base + (size_t)(bn + row) * 512 + k0 + cp * 8;
            *(h8*)&Bs[swz(row, cp)]     = ((const h8*)bp)[0];
            *(h8*)&Bs[swz(row, cp + 1)] = ((const h8*)bp)[1];
        }
        __syncthreads();

        h8 a[4], bb[4];
#pragma unroll
        for (int mi = 0; mi < 4; ++mi) a[mi] = *(const h8*)&As[swz(wm * 64 + mi * 16 + c, q)];
#pragma unroll
        for (int ni = 0; ni < 4; ++ni) bb[ni] = *(const h8*)&Bs[swz(wn * 64 + ni * 16 + c, q)];
#pragma unroll
        for (int mi = 0; mi < 4; ++mi)
#pragma unroll
            for (int ni = 0; ni < 4; ++ni)
                acc[mi][ni] = __builtin_amdgcn_mfma_f32_16x16x32_f16(a[mi], bb[ni], acc[mi][ni], 0, 0, 0);
        __syncthreads();
    }

#pragma unroll
    for (int mi = 0; mi < 4; ++mi)
#pragma unroll
        for (int ni = 0; ni < 4; ++ni) {
            int col = bn + wn * 64 + ni * 16 + c;
            int rowb = bm + wm * 64 + mi * 16 + q * 4;
#pragma unroll
            for (int r = 0; r < 4; ++r)
                Cout[base + (size_t)(rowb + r) * 512 + col] = acc[mi][ni][r];
        }
}

extern "C" void kernel_launch(void* const* d_in, const int* in_sizes, int n_in,
                              void* d_out, int out_size, void* d_ws, size_t ws_size,
                              hipStream_t stream) {
    const float* P = (const float*)d_in[0];
    const float* H = (const float*)d_in[1];
    const float* W = (const float*)d_in[2];
    float* out = (float*)d_out;

    _Float16* ws16 = (_Float16*)d_ws;
    _Float16* F    = ws16;                       // F_p|F_h: 2*16777216 (dead after score)
    _Float16* PT   = ws16;                       // reuses F region after score
    _Float16* HT   = ws16 + TOT_ELEMS;
    _Float16* attn = ws16 + 2 * TOT_ELEMS;       // 16777216
    _Float16* WTH  = attn;                       // WT lives in attn region (dead
    _Float16* WTL  = attn + BATCH_ELEMS;         //  before score writes attn)

    transpose_f16_kernel<true><<<dim3(8, 8, 1), 256, 0, stream>>>(W, WTH, WTL);
    proj_tanh_kernel<<<dim3(256, 4, 2), 256, 0, stream>>>(P, H, WTH, WTL, F);
    score_softmax_kernel<<<dim3(8, NB), 256, 0, stream>>>(F, attn);
    transpose_f16_kernel<false><<<dim3(8, 8, NB), 256, 0, stream>>>(H, HT, nullptr);
    transpose_f16_kernel<false><<<dim3(8, 8, NB), 256, 0, stream>>>(P, PT, nullptr);
    out_gemm_kernel<false><<<dim3(4, 4, NB), 256, 0, stream>>>(attn, HT, out);
    out_gemm_kernel<true><<<dim3(4, 4, NB), 256, 0, stream>>>(attn, PT, out + TOT_ELEMS);
}